// Round 12
// baseline (42.071 us; speedup 1.0000x reference)
//
#include <hip/hip_runtime.h>

// LocallyConnected2d: x(16,3,128,128) f32, W(61,61,64,3,8,8) f32, bias(64,61,61) f32
// out(16,1,488,488) f32; stride 2, kernel 8, no pad; pixel-shuffle r=8 epilogue.
//
// R10: hybrid of the two validated halves. x staged cooperatively in LDS
// (6 KB, coalesced, rotation-swizzled rows -- R9's mapping); W streams DIRECT
// global -> reg -> cvt_pkrtz -> MFMA B-frag (R7/R8's coalesced pattern: lane
// (lq,lk) reads W[oc][ks*32+lk*8..+8]; 16 fully-consumed lines per instr
// pair). No W LDS round-trip. Load order: x first, then W -- phase 2 (x cvt +
// LDS write) retires at vmcnt(12) while the 12 W loads stay in flight; the
// ks-loop drains them progressively. 6 KB LDS; occupancy = wave-slot bound
// (256,5) = 20 waves/CU; ~90 VGPR (spill-free under the 102 cap).
// C layout (validated R6b/R9): row(batch)=lk*4+r, col(oc)=lq.

namespace {
constexpr int NHW  = 61 * 61;       // 3721
constexpr int XB   = 3 * 128 * 128;
constexpr int XCC  = 128 * 128;
constexpr int OSTR = 488 * 488;
}

typedef __fp16   fp16x2 __attribute__((ext_vector_type(2)));
typedef _Float16 half8v __attribute__((ext_vector_type(8)));
typedef float    f32x4  __attribute__((ext_vector_type(4)));

union H8 { fp16x2 p[4]; half8v h; uint4 u; };

__global__ __launch_bounds__(256, 5) void lc2d_kernel(
    const float* __restrict__ xg,   // [16][3][128][128]
    const float* __restrict__ wg,   // [61][61][64][3][8][8]
    const float* __restrict__ bg,   // [64][61][61]
    float* __restrict__ og)         // [16][488][488]
{
    __shared__ __align__(16) _Float16 xlh[16 * 192];   // 6 KB

    const int hw   = blockIdx.x;
    const int h    = hw / 61;
    const int w    = hw - h * 61;
    const int t    = threadIdx.x;
    const int lane = t & 63;
    const int wv   = t >> 6;

    const int lq = lane & 15;       // A row (batch) / B col (oc)
    const int lk = lane >> 4;       // k-run selector
    const int oc = wv * 16 + lq;

    // ---- phase 1a: x stage loads FIRST (L2-resident, retire early) ------
    const float* xb = xg + (h * 2) * 128 + (w * 2);
    float2 xr[6];
    #pragma unroll
    for (int it = 0; it < 6; ++it) {
        const int f  = it * 256 + t;        // float2 slot 0..1535
        const int b  = f / 96;
        const int r  = f - b * 96;
        const int k  = r * 2;
        const int c  = k >> 6;              // channel
        const int i  = (k >> 3) & 7;        // kernel row
        const int j  = k & 7;               // within-run offset (even)
        xr[it] = *reinterpret_cast<const float2*>(xb + b * XB + c * XCC + i * 128 + j);
    }
    // ---- phase 1b: W direct loads (12 independent dwordx4, stay in flight)
    const float* wrow = wg + ((size_t)hw * 64 + oc) * 192 + lk * 8;
    float4 wr[12];
    #pragma unroll
    for (int ks = 0; ks < 6; ++ks) {
        wr[ks * 2]     = *reinterpret_cast<const float4*>(wrow + ks * 32);
        wr[ks * 2 + 1] = *reinterpret_cast<const float4*>(wrow + ks * 32 + 4);
    }
    __builtin_amdgcn_sched_barrier(0);      // pin issue order / keep batch up front

    // ---- phase 2: x convert + LDS write (needs only the 6 x loads) ------
    #pragma unroll
    for (int it = 0; it < 6; ++it) {
        const int f  = it * 256 + t;
        const int b  = f / 96;
        const int r  = f - b * 96;
        const int s8 = r >> 2;
        const int j  = (r & 3) * 2;
        const fp16x2 pk = __builtin_amdgcn_cvt_pkrtz(xr[it].x, xr[it].y);
        int srot = s8 + (b & 7); if (srot >= 24) srot -= 24;
        union { fp16x2 p; unsigned u; } cv; cv.p = pk;
        *reinterpret_cast<unsigned*>(&xlh[b * 192 + srot * 8 + j]) = cv.u;
    }
    __syncthreads();

    // ---- phase 3: 6 k-steps; A from LDS, B from W regs (cvt in loop) ----
    f32x4 acc = {0.f, 0.f, 0.f, 0.f};
    #pragma unroll
    for (int ks = 0; ks < 6; ++ks) {
        const int slog = ks * 4 + lk;
        int sa = slog + (lq & 7); if (sa >= 24) sa -= 24;
        const half8v av = *reinterpret_cast<const half8v*>(&xlh[lq * 192 + sa * 8]);
        H8 bv;
        bv.p[0] = __builtin_amdgcn_cvt_pkrtz(wr[ks*2].x,   wr[ks*2].y);
        bv.p[1] = __builtin_amdgcn_cvt_pkrtz(wr[ks*2].z,   wr[ks*2].w);
        bv.p[2] = __builtin_amdgcn_cvt_pkrtz(wr[ks*2+1].x, wr[ks*2+1].y);
        bv.p[3] = __builtin_amdgcn_cvt_pkrtz(wr[ks*2+1].z, wr[ks*2+1].w);
        acc = __builtin_amdgcn_mfma_f32_16x16x32_f16(av, bv.h, acc, 0, 0, 0);
    }

    // ---- epilogue: bias + pixel-shuffle store ---------------------------
    const float bz = bg[oc * NHW + hw];
    float* ob = og + (h * 8 + (oc >> 3)) * 488 + (w * 8 + (oc & 7));
    #pragma unroll
    for (int r = 0; r < 4; ++r) {
        const int b = lk * 4 + r;           // batch = C row
        ob[(size_t)b * OSTR] = acc[r] + bz;
    }
}

extern "C" void kernel_launch(void* const* d_in, const int* in_sizes, int n_in,
                              void* d_out, int out_size, void* d_ws, size_t ws_size,
                              hipStream_t stream) {
    const float* x    = (const float*)d_in[0];
    const float* W    = (const float*)d_in[1];
    const float* bias = (const float*)d_in[2];
    float* out        = (float*)d_out;
    lc2d_kernel<<<dim3(NHW), dim3(256), 0, stream>>>(x, W, bias, out);
}

// Round 13
// 40.137 us; speedup vs baseline: 1.0482x; 1.0482x over previous
//
#include <hip/hip_runtime.h>

// LocallyConnected2d: x(16,3,128,128) f32, W(61,61,64,3,8,8) f32, bias(64,61,61) f32
// out(16,1,488,488) f32; stride 2, kernel 8, no pad; pixel-shuffle r=8 epilogue.
//
// R11: R9's staging (load-ALL-then-convert, linear W stream) in 128-thread
// blocks covering 32 ocs (hw split in half). LDS = 12 KB W(f16) + 6 KB x(f16)
// = 18 KB -> 8 blocks/CU: 8 phase-staggered pipelines per CU hide the
// staging-barrier tail that capped R9 (5 pipelines). Per-thread MLP = 24
// in-flight loads (12 W float4 + 12 x float2). Compute = validated R6b/R9:
// rotation-swizzled rows (slot=(s8+row&7)%24, 2-way free), 6x
// mfma_f32_16x16x32_f16, C: row(batch)=lk*4+r, col(oc)=lq.

namespace {
constexpr int NHW  = 61 * 61;       // 3721
constexpr int XB   = 3 * 128 * 128;
constexpr int XCC  = 128 * 128;
constexpr int OSTR = 488 * 488;
}

typedef __fp16   fp16x2 __attribute__((ext_vector_type(2)));
typedef _Float16 half8v __attribute__((ext_vector_type(8)));
typedef float    f32x4  __attribute__((ext_vector_type(4)));

union H8 { fp16x2 p[4]; half8v h; uint4 u; };

__global__ __launch_bounds__(128, 4) void lc2d_kernel(
    const float* __restrict__ xg,   // [16][3][128][128]
    const float* __restrict__ wg,   // [61][61][64][3][8][8]
    const float* __restrict__ bg,   // [64][61][61]
    float* __restrict__ og)         // [16][488][488]
{
    __shared__ __align__(16) _Float16 wlh[32 * 192];   // 12 KB
    __shared__ __align__(16) _Float16 xlh[16 * 192];   //  6 KB

    const int bid  = blockIdx.x;
    const int hw   = bid >> 1;
    const int half = bid & 1;       // which 32-oc half
    const int h    = hw / 61;
    const int w    = hw - h * 61;
    const int t    = threadIdx.x;
    const int lane = t & 63;
    const int wv   = t >> 6;        // 2 waves

    const float* wbase = wg + ((size_t)hw * 64 + half * 32) * 192;
    const float* xb    = xg + (h * 2) * 128 + (w * 2);

    // ---- phase 1: issue ALL staging loads as one batch ------------------
    // W: 768 groups of 8 floats; thread handles g = it*128+t, it<6.
    float4 wr[12];
    #pragma unroll
    for (int it = 0; it < 6; ++it) {
        const int g  = it * 128 + t;
        const int oc = g / 24;
        const int s8 = g - oc * 24;
        const float* src = wbase + oc * 192 + s8 * 8;
        wr[it * 2]     = *reinterpret_cast<const float4*>(src);
        wr[it * 2 + 1] = *reinterpret_cast<const float4*>(src + 4);
    }
    // x: 1536 float2; thread handles f = it*128+t, it<12.
    float2 xr[12];
    #pragma unroll
    for (int it = 0; it < 12; ++it) {
        const int f  = it * 128 + t;
        const int b  = f / 96;
        const int r  = f - b * 96;
        const int k  = r * 2;
        const int c  = k >> 6;              // channel
        const int i  = (k >> 3) & 7;        // kernel row
        const int j  = k & 7;               // within-run offset (even)
        xr[it] = *reinterpret_cast<const float2*>(xb + b * XB + c * XCC + i * 128 + j);
    }
    __builtin_amdgcn_sched_barrier(0);      // keep the whole batch in flight

    // ---- phase 2: convert + LDS write -----------------------------------
    #pragma unroll
    for (int it = 0; it < 6; ++it) {
        const int g  = it * 128 + t;
        const int oc = g / 24;
        const int s8 = g - oc * 24;
        H8 u;
        u.p[0] = __builtin_amdgcn_cvt_pkrtz(wr[it*2].x,   wr[it*2].y);
        u.p[1] = __builtin_amdgcn_cvt_pkrtz(wr[it*2].z,   wr[it*2].w);
        u.p[2] = __builtin_amdgcn_cvt_pkrtz(wr[it*2+1].x, wr[it*2+1].y);
        u.p[3] = __builtin_amdgcn_cvt_pkrtz(wr[it*2+1].z, wr[it*2+1].w);
        int srot = s8 + (oc & 7); if (srot >= 24) srot -= 24;
        *reinterpret_cast<uint4*>(&wlh[oc * 192 + srot * 8]) = u.u;
    }
    #pragma unroll
    for (int it = 0; it < 12; ++it) {
        const int f  = it * 128 + t;
        const int b  = f / 96;
        const int r  = f - b * 96;
        const int s8 = r >> 2;
        const int j  = (r & 3) * 2;
        const fp16x2 pk = __builtin_amdgcn_cvt_pkrtz(xr[it].x, xr[it].y);
        int srot = s8 + (b & 7); if (srot >= 24) srot -= 24;
        union { fp16x2 p; unsigned u; } cv; cv.p = pk;
        *reinterpret_cast<unsigned*>(&xlh[b * 192 + srot * 8 + j]) = cv.u;
    }
    __syncthreads();

    // ---- phase 3: MFMA (wave wv -> local ocs wv*16..+16) ----------------
    const int lq  = lane & 15;          // A row (batch) / B col (oc)
    const int lk  = lane >> 4;          // k-run selector
    const int ocl = wv * 16 + lq;       // row in wlh (0..31)

    f32x4 acc = {0.f, 0.f, 0.f, 0.f};
    #pragma unroll
    for (int ks = 0; ks < 6; ++ks) {
        const int slog = ks * 4 + lk;
        int sa = slog + (lq & 7);   if (sa >= 24) sa -= 24;
        int sb = slog + (ocl & 7);  if (sb >= 24) sb -= 24;
        const half8v av = *reinterpret_cast<const half8v*>(&xlh[lq  * 192 + sa * 8]);
        const half8v bv = *reinterpret_cast<const half8v*>(&wlh[ocl * 192 + sb * 8]);
        acc = __builtin_amdgcn_mfma_f32_16x16x32_f16(av, bv, acc, 0, 0, 0);
    }

    // ---- epilogue: bias + pixel-shuffle store ---------------------------
    const int   ocg = half * 32 + ocl;
    const float bz  = bg[ocg * NHW + hw];
    float* ob = og + (h * 8 + (ocg >> 3)) * 488 + (w * 8 + (ocg & 7));
    #pragma unroll
    for (int r = 0; r < 4; ++r) {
        const int b = lk * 4 + r;       // batch = C row
        ob[(size_t)b * OSTR] = acc[r] + bz;
    }
}

extern "C" void kernel_launch(void* const* d_in, const int* in_sizes, int n_in,
                              void* d_out, int out_size, void* d_ws, size_t ws_size,
                              hipStream_t stream) {
    const float* x    = (const float*)d_in[0];
    const float* W    = (const float*)d_in[1];
    const float* bias = (const float*)d_in[2];
    float* out        = (float*)d_out;
    lc2d_kernel<<<dim3(NHW * 2), dim3(128), 0, stream>>>(x, W, bias, out);
}